// Round 9
// baseline (176.018 us; speedup 1.0000x reference)
//
#include <hip/hip_runtime.h>
#include <hip/hip_cooperative_groups.h>
#include <stdint.h>

// Problem constants: B=4, N=8192, G=512, E=512, D=3E=1536
#define NP 8192
#define NG 512
#define DF 1536

namespace cg = cooperative_groups;

using f32x4    = __attribute__((ext_vector_type(4))) float;
using bf16x8   = __attribute__((ext_vector_type(8))) __bf16;
using ushort8v = __attribute__((ext_vector_type(8))) unsigned short;

// Swizzled bf16 operand layout ("fragment order"): matrix [R rows][K cols],
// block b = (r>>4)*(K/32) + (k>>5) holds 16 rows x 32 k as 512 contiguous
// elems; offset = lane*8, lane = ((k>>3)&3)*16 + (r&15). A wave's MFMA
// fragment load is then ONE contiguous 1KB global_load_dwordx4 (or ds_read_b128).

__device__ __forceinline__ unsigned short f32_to_bf16(float f) {
  unsigned int u = __float_as_uint(f);
  u += 0x7fffu + ((u >> 16) & 1u);   // round-to-nearest-even
  return (unsigned short)(u >> 16);
}
__device__ __forceinline__ float bf2f(unsigned short u) {
  return __uint_as_float(((unsigned)u) << 16);
}

struct FusedArgs {
  const float *xyz, *centers, *H4, *H8, *H12, *w1, *w2;
  const float *g1, *be1, *m1, *v1, *g2, *be2, *m2, *v2, *b1, *b2;
  unsigned short *fswz, *w1s, *w2s, *Amatb;
  int *nidx; float *nw, *s1, *t1, *s2, *t2;
  float *outp;
};

// ============ Phase 1 unit: knn / swizzle-casts / BN fold ===================
// units: [0,512) knn | [512,2048) fused | [2048,2432) w1 | [2432,2560) w2 | 2560 scales
__device__ void phase_setup(const FusedArgs& a, char* smem, int w) {
  const int tid = threadIdx.x;
  if (w < 512) {
    // ---- KNN: 4 lanes/point, branchless top-3, shfl merge ----
    float4* cs = (float4*)smem;            // [4*129] = 8256 B
    const int b = w >> 7;
    for (int i = tid; i < NG; i += 256) {
      float c0 = a.centers[((size_t)b * NG + i) * 3 + 0];
      float c1 = a.centers[((size_t)b * NG + i) * 3 + 1];
      float c2 = a.centers[((size_t)b * NG + i) * 3 + 2];
      float4 v; v.x = c0; v.y = c1; v.z = c2; v.w = c0 * c0 + c1 * c1 + c2 * c2;
      cs[(i >> 7) * 129 + (i & 127)] = v;
    }
    __syncthreads();
    const int t = (w & 127) * 256 + tid;
    const int p = t >> 2, q = t & 3;
    const size_t pi = (size_t)b * NP + p;
    const float x0 = a.xyz[pi * 3 + 0], x1 = a.xyz[pi * 3 + 1], x2 = a.xyz[pi * 3 + 2];
    const float xx = x0 * x0 + x1 * x1 + x2 * x2;
    float d0 = 3.4e38f, d1 = 3.4e38f, d2 = 3.4e38f;
    int i0 = 0, i1 = 0, i2 = 0;
    const int gbase = q * 128;
    const float4* csq = cs + q * 129;
#pragma unroll 4
    for (int j = 0; j < 128; ++j) {
      float4 c = csq[j];
      float d = xx + c.w - 2.0f * (x0 * c.x + x1 * c.y + x2 * c.z);
      int g = gbase + j;
      bool c0 = d < d0, c1 = d < d1, c2 = d < d2;
      float nd2 = c1 ? d1 : (c2 ? d : d2); int ni2 = c1 ? i1 : (c2 ? g : i2);
      float nd1 = c0 ? d0 : (c1 ? d : d1); int ni1 = c0 ? i0 : (c1 ? g : i1);
      d0 = c0 ? d : d0;                    i0 = c0 ? g : i0;
      d1 = nd1; i1 = ni1; d2 = nd2; i2 = ni2;
    }
#pragma unroll
    for (int off = 1; off <= 2; off <<= 1) {
      float e0 = __shfl_xor(d0, off), e1 = __shfl_xor(d1, off), e2 = __shfl_xor(d2, off);
      int j0 = __shfl_xor(i0, off), j1 = __shfl_xor(i1, off), j2 = __shfl_xor(i2, off);
#pragma unroll
      for (int s = 0; s < 3; ++s) {
        float e = (s == 0) ? e0 : (s == 1 ? e1 : e2);
        int   j = (s == 0) ? j0 : (s == 1 ? j1 : j2);
        bool c0 = (e < d0) || (e == d0 && j < i0);
        bool c1 = (e < d1) || (e == d1 && j < i1);
        bool c2 = (e < d2) || (e == d2 && j < i2);
        float nd2 = c1 ? d1 : (c2 ? e : d2); int ni2 = c1 ? i1 : (c2 ? j : i2);
        float nd1 = c0 ? d0 : (c1 ? e : d1); int ni1 = c0 ? i0 : (c1 ? j : i1);
        d0 = c0 ? e : d0;                    i0 = c0 ? j : i0;
        d1 = nd1; i1 = ni1; d2 = nd2; i2 = ni2;
      }
    }
    if (q == 0) {
      float r0 = 1.0f / (d0 + 1e-8f), r1 = 1.0f / (d1 + 1e-8f), r2 = 1.0f / (d2 + 1e-8f);
      float inv = 1.0f / (r0 + r1 + r2);
      a.nw[pi * 3 + 0] = r0 * inv; a.nw[pi * 3 + 1] = r1 * inv; a.nw[pi * 3 + 2] = r2 * inv;
      a.nidx[pi * 3 + 0] = i0; a.nidx[pi * 3 + 1] = i1; a.nidx[pi * 3 + 2] = i2;
    }
    __syncthreads();
  } else if (w < 2048) {
    // ---- fused=concat(H4,H8,H12) [2048,1536] f32 -> bf16 SWIZZLED ----
    const int qd = (w - 512) * 256 + tid;
    const int L = qd & 63, t2 = qd >> 6;
    const int kc = t2 % 48, mg = t2 / 48;
    const int m = mg * 16 + (L & 15);
    const int k = kc * 32 + (L >> 4) * 8;
    const float* src = (k < 512) ? a.H4 : (k < 1024 ? a.H8 : a.H12);
    const float* sp = &src[(size_t)m * 512 + (k & 511)];
    float4 va = *(const float4*)sp, vb = *(const float4*)(sp + 4);
    ushort8v o;
    o[0] = f32_to_bf16(va.x); o[1] = f32_to_bf16(va.y);
    o[2] = f32_to_bf16(va.z); o[3] = f32_to_bf16(va.w);
    o[4] = f32_to_bf16(vb.x); o[5] = f32_to_bf16(vb.y);
    o[6] = f32_to_bf16(vb.z); o[7] = f32_to_bf16(vb.w);
    *(ushort8v*)&a.fswz[((size_t)(mg * 48 + kc)) * 512 + L * 8] = o;
  } else if (w < 2432) {
    // ---- w1 [512,1536] -> bf16 SWIZZLED ----
    const int qd = (w - 2048) * 256 + tid;
    const int L = qd & 63, t2 = qd >> 6;
    const int kc = t2 % 48, ng = t2 / 48;
    const int n = ng * 16 + (L & 15);
    const int k = kc * 32 + (L >> 4) * 8;
    const float* sp = &a.w1[(size_t)n * 1536 + k];
    float4 va = *(const float4*)sp, vb = *(const float4*)(sp + 4);
    ushort8v o;
    o[0] = f32_to_bf16(va.x); o[1] = f32_to_bf16(va.y);
    o[2] = f32_to_bf16(va.z); o[3] = f32_to_bf16(va.w);
    o[4] = f32_to_bf16(vb.x); o[5] = f32_to_bf16(vb.y);
    o[6] = f32_to_bf16(vb.z); o[7] = f32_to_bf16(vb.w);
    *(ushort8v*)&a.w1s[((size_t)(ng * 48 + kc)) * 512 + L * 8] = o;
  } else if (w < 2560) {
    // ---- w2 [512,512] -> bf16 SWIZZLED ----
    const int qd = (w - 2432) * 256 + tid;
    const int L = qd & 63, t2 = qd >> 6;
    const int kc = t2 & 15, ng = t2 >> 4;
    const int n = ng * 16 + (L & 15);
    const int k = kc * 32 + (L >> 4) * 8;
    const float* sp = &a.w2[(size_t)n * 512 + k];
    float4 va = *(const float4*)sp, vb = *(const float4*)(sp + 4);
    ushort8v o;
    o[0] = f32_to_bf16(va.x); o[1] = f32_to_bf16(va.y);
    o[2] = f32_to_bf16(va.z); o[3] = f32_to_bf16(va.w);
    o[4] = f32_to_bf16(vb.x); o[5] = f32_to_bf16(vb.y);
    o[6] = f32_to_bf16(vb.z); o[7] = f32_to_bf16(vb.w);
    *(ushort8v*)&a.w2s[((size_t)(ng * 16 + kc)) * 512 + L * 8] = o;
  } else {
    // ---- BN constant folding ----
    for (int i = tid; i < 512; i += 256) {
      float sa = a.g1[i] / sqrtf(a.v1[i] + 1e-5f);
      a.s1[i] = sa; a.t1[i] = a.be1[i] - a.m1[i] * sa;
      float sb = a.g2[i] / sqrtf(a.v2[i] + 1e-5f);
      a.s2[i] = sb; a.t2[i] = a.be2[i] - a.m2[i] * sb;
    }
  }
}

// ============ Phase 2: GEMM1  Amatb = bf16(s1*(fused.w1^T + b1) + t1) =======
// 1024 blocks, 32x32 tile (64 m-tiles x 16 n-tiles), barrier-free
// wave-split-K (4 waves x K=384), acc 2x2, LDS reduce.
__device__ void phase_gemm1(const FusedArgs& a, char* smem) {
  float* red = (float*)smem;               // [32*33] = 4224 B
  const int tid = threadIdx.x, lane = tid & 63, wv = tid >> 6;
  const int blk = blockIdx.x;
  const int m0 = (blk >> 4) * 32;
  const int n0 = (blk & 15) * 32;
  const unsigned short* Ap = a.fswz + ((size_t)(m0 >> 4) * 48 + wv * 12) * 512 + lane * 8;
  const unsigned short* Bp = a.w1s  + ((size_t)(n0 >> 4) * 48 + wv * 12) * 512 + lane * 8;

  f32x4 acc[2][2];
#pragma unroll
  for (int i = 0; i < 2; ++i)
#pragma unroll
    for (int j = 0; j < 2; ++j) acc[i][j] = (f32x4){0.f, 0.f, 0.f, 0.f};

  bf16x8 af[2], bfr[2], afn[2], bfn[2];
#pragma unroll
  for (int i = 0; i < 2; ++i) {
    af[i]  = __builtin_bit_cast(bf16x8, *(const ushort8v*)(Ap + (size_t)i * 48 * 512));
    bfr[i] = __builtin_bit_cast(bf16x8, *(const ushort8v*)(Bp + (size_t)i * 48 * 512));
  }
#pragma unroll 1
  for (int kc = 0; kc < 12; ++kc) {
    if (kc < 11) {
#pragma unroll
      for (int i = 0; i < 2; ++i) {
        afn[i] = __builtin_bit_cast(bf16x8, *(const ushort8v*)(Ap + (size_t)i * 48 * 512 + (kc + 1) * 512));
        bfn[i] = __builtin_bit_cast(bf16x8, *(const ushort8v*)(Bp + (size_t)i * 48 * 512 + (kc + 1) * 512));
      }
    }
#pragma unroll
    for (int mi = 0; mi < 2; ++mi)
#pragma unroll
      for (int ni = 0; ni < 2; ++ni)
        acc[mi][ni] = __builtin_amdgcn_mfma_f32_16x16x32_bf16(af[mi], bfr[ni], acc[mi][ni], 0, 0, 0);
#pragma unroll
    for (int i = 0; i < 2; ++i) { af[i] = afn[i]; bfr[i] = bfn[i]; }
  }

  // 4-way cross-wave reduce through LDS
  for (int w = 0; w < 4; ++w) {
    if (wv == w) {
#pragma unroll
      for (int mi = 0; mi < 2; ++mi)
#pragma unroll
        for (int ni = 0; ni < 2; ++ni) {
          int col = ni * 16 + (lane & 15);
#pragma unroll
          for (int r = 0; r < 4; ++r) {
            int row = mi * 16 + (lane >> 4) * 4 + r;
            if (w == 0) red[row * 33 + col] = acc[mi][ni][r];
            else        red[row * 33 + col] += acc[mi][ni][r];
          }
        }
    }
    __syncthreads();
  }
  // epilogue: affine -> bf16 (relu deferred to mega), 8B stores
  const int row = tid >> 3;               // 0..31
  const int col = (tid & 7) * 4;          // 0..28
  ushort4 o;
  float v0 = red[row * 33 + col + 0], v1 = red[row * 33 + col + 1];
  float v2 = red[row * 33 + col + 2], v3 = red[row * 33 + col + 3];
  int n = n0 + col;
  o.x = f32_to_bf16(a.s1[n + 0] * (v0 + a.b1[n + 0]) + a.t1[n + 0]);
  o.y = f32_to_bf16(a.s1[n + 1] * (v1 + a.b1[n + 1]) + a.t1[n + 1]);
  o.z = f32_to_bf16(a.s1[n + 2] * (v2 + a.b1[n + 2]) + a.t1[n + 2]);
  o.w = f32_to_bf16(a.s1[n + 3] * (v3 + a.b1[n + 3]) + a.t1[n + 3]);
  *(ushort4*)&a.Amatb[(size_t)(m0 + row) * 512 + n] = o;
  __syncthreads();
}

// ============ Phase 3: MEGA  interp->LDS then GEMM2 -> out ==================
// 1024 blocks; block = 32 points x all 512 outputs. XCD swizzle: each XCD owns
// a contiguous 4096-point range -> its Amatb batch slice (512KB) L2-resident.
// Stage 1: 2 waves per 16-point rowgroup (8 k-chunks each), gather Amatb (L2)
// -> 32KB LDS tile in fragment order (lane*16B contiguous, conflict-free).
// Stage 2: wave per 128-n slice, acc 2x8 (B-frags in 2 groups of 4 to cap
// VGPR pressure ~100 < 128), K=512; B from L2-resident w2s; nt out stores.
__device__ void phase_mega(const FusedArgs& a, char* smem) {
  unsigned short* hl = (unsigned short*)smem;   // [32*512] bf16, fragment order
  const int tid = threadIdx.x, lane = tid & 63, wv = tid >> 6;
  const int xcd = blockIdx.x & 7, slot = blockIdx.x >> 3;   // slot 0..127
  const int m0 = xcd * 4096 + slot * 32;

  // ---- stage 1: interp 32x512 into LDS ----
  {
    const int g = wv >> 1, half = wv & 1;      // rowgroup, k-half
    const int p = m0 + g * 16 + (lane & 15);
    const int b = p >> 13;
    const int i0 = a.nidx[p * 3 + 0], i1 = a.nidx[p * 3 + 1], i2 = a.nidx[p * 3 + 2];
    const float w0 = a.nw[p * 3 + 0], w1v = a.nw[p * 3 + 1], w2v = a.nw[p * 3 + 2];
    const int co = (lane >> 4) * 8;
    const unsigned short* A0 = a.Amatb + ((size_t)(b * 512 + i0)) * 512 + co;
    const unsigned short* A1 = a.Amatb + ((size_t)(b * 512 + i1)) * 512 + co;
    const unsigned short* A2 = a.Amatb + ((size_t)(b * 512 + i2)) * 512 + co;
    unsigned short* wp = hl + (size_t)g * 16 * 512 + lane * 8;
#pragma unroll
    for (int i = 0; i < 8; ++i) {
      const int kc = half * 8 + i;
      ushort8v u0 = *(const ushort8v*)(A0 + kc * 32);
      ushort8v u1 = *(const ushort8v*)(A1 + kc * 32);
      ushort8v u2 = *(const ushort8v*)(A2 + kc * 32);
      ushort8v o;
#pragma unroll
      for (int j = 0; j < 8; ++j) {
        float v = w0 * bf2f(u0[j]) + w1v * bf2f(u1[j]) + w2v * bf2f(u2[j]);
        o[j] = f32_to_bf16(fmaxf(v, 0.f));
      }
      *(ushort8v*)(wp + (size_t)kc * 512) = o;
    }
  }
  __syncthreads();

  // ---- stage 2: out[m0..m0+31][:] = relu(s2*(hl . w2s^T + b2) + t2) ----
  const int n0 = wv * 128;
  const unsigned short* Bbase = a.w2s + (size_t)(n0 >> 4) * 16 * 512 + lane * 8;

  f32x4 acc[2][8];
#pragma unroll
  for (int i = 0; i < 2; ++i)
#pragma unroll
    for (int j = 0; j < 8; ++j) acc[i][j] = (f32x4){0.f, 0.f, 0.f, 0.f};

#pragma unroll 1
  for (int kc = 0; kc < 16; ++kc) {
    bf16x8 af[2];
#pragma unroll
    for (int g = 0; g < 2; ++g)
      af[g] = __builtin_bit_cast(bf16x8,
          *(const ushort8v*)(hl + (size_t)(g * 16 + kc) * 512 + lane * 8));
#pragma unroll
    for (int grp = 0; grp < 2; ++grp) {
      bf16x8 bfr[4];
#pragma unroll
      for (int j = 0; j < 4; ++j)
        bfr[j] = __builtin_bit_cast(bf16x8,
            *(const ushort8v*)(Bbase + (size_t)((grp * 4 + j) * 16 + kc) * 512));
#pragma unroll
      for (int mi = 0; mi < 2; ++mi)
#pragma unroll
        for (int j = 0; j < 4; ++j)
          acc[mi][grp * 4 + j] = __builtin_amdgcn_mfma_f32_16x16x32_bf16(
              af[mi], bfr[j], acc[mi][grp * 4 + j], 0, 0, 0);
    }
  }

  // C/D layout: n = lane&15, m = (lane>>4)*4 + reg   [m89-verified]
#pragma unroll
  for (int mi = 0; mi < 2; ++mi) {
    int mbase = m0 + mi * 16 + (lane >> 4) * 4;
#pragma unroll
    for (int ni = 0; ni < 8; ++ni) {
      int n = n0 + ni * 16 + (lane & 15);
      float s = a.s2[n], bb = a.b2[n], t = a.t2[n];
      f32x4 v = acc[mi][ni];
#pragma unroll
      for (int r = 0; r < 4; ++r)
        __builtin_nontemporal_store(fmaxf(s * (v[r] + bb) + t, 0.f),
                                    &a.outp[(size_t)(mbase + r) * 512 + n]);
    }
  }
}

// ============ cooperative fused kernel: 1024 blocks, 4 blocks/CU ============
__global__ __launch_bounds__(256, 4) void fused_kernel(FusedArgs a) {
  __shared__ __align__(16) char smem[32768];
  cg::grid_group grid = cg::this_grid();
  const int blk = blockIdx.x;
  for (int u = blk; u <= 2560; u += 1024) phase_setup(a, smem, u);
  grid.sync();
  phase_gemm1(a, smem);
  grid.sync();
  phase_mega(a, smem);
}

// ============ fallback standalone kernels (same device code) ================
__global__ __launch_bounds__(256, 4) void k_setup(FusedArgs a) {
  __shared__ __align__(16) char smem[8448];
  for (int u = blockIdx.x; u <= 2560; u += 1024) phase_setup(a, smem, u);
}
__global__ __launch_bounds__(256, 4) void k_gemm1(FusedArgs a) {
  __shared__ __align__(16) char smem[4224];
  phase_gemm1(a, smem);
}
__global__ __launch_bounds__(256, 4) void k_mega(FusedArgs a) {
  __shared__ __align__(16) char smem[32768];
  phase_mega(a, smem);
}

extern "C" void kernel_launch(void* const* d_in, const int* in_sizes, int n_in,
                              void* d_out, int out_size, void* d_ws, size_t ws_size,
                              hipStream_t stream) {
  char* ws = (char*)d_ws;
  FusedArgs a;
  a.xyz     = (const float*)d_in[0];
  a.centers = (const float*)d_in[1];
  a.H4      = (const float*)d_in[2];
  a.H8      = (const float*)d_in[3];
  a.H12     = (const float*)d_in[4];
  a.w1      = (const float*)d_in[5];
  a.b1      = (const float*)d_in[6];
  a.g1      = (const float*)d_in[7];
  a.be1     = (const float*)d_in[8];
  a.m1      = (const float*)d_in[9];
  a.v1      = (const float*)d_in[10];
  a.w2      = (const float*)d_in[11];
  a.b2      = (const float*)d_in[12];
  a.g2      = (const float*)d_in[13];
  a.be2     = (const float*)d_in[14];
  a.m2      = (const float*)d_in[15];
  a.v2      = (const float*)d_in[16];
  a.fswz  = (unsigned short*)(ws);                // 6,291,456 B
  a.w1s   = (unsigned short*)(ws + 6291456);      // 1,572,864 B
  a.w2s   = (unsigned short*)(ws + 7864320);      //   524,288 B
  a.Amatb = (unsigned short*)(ws + 8388608);      // 2,097,152 B (bf16)
  a.nidx  = (int*)           (ws + 10485760);     //   393,216 B
  a.nw    = (float*)         (ws + 10878976);     //   393,216 B
  a.s1    = (float*)         (ws + 11272192);
  a.t1 = a.s1 + 512; a.s2 = a.t1 + 512; a.t2 = a.s2 + 512;
  a.outp  = (float*)d_out;

  // Occupancy-gated cooperative launch: pure host query (capture-safe).
  int nb = 0;
  hipError_t qerr = hipOccupancyMaxActiveBlocksPerMultiprocessor(
      &nb, reinterpret_cast<const void*>(fused_kernel), 256, 0);
  bool coop_ok = (qerr == hipSuccess) && (nb >= 4);
  if (coop_ok) {
    void* kp[] = { (void*)&a };
    hipError_t lerr = hipLaunchCooperativeKernel(
        (const void*)fused_kernel, dim3(1024), dim3(256), kp, 0, stream);
    coop_ok = (lerr == hipSuccess);
  }
  if (!coop_ok) {
    k_setup <<<1024, 256, 0, stream>>>(a);
    k_gemm1 <<<1024, 256, 0, stream>>>(a);
    k_mega  <<<1024, 256, 0, stream>>>(a);
  }
}